// Round 4
// baseline (245.108 us; speedup 1.0000x reference)
//
#include <hip/hip_runtime.h>

typedef float v2f __attribute__((ext_vector_type(2)));

#define HH 1024
#define WW 1024
#define NB 4
#define NC 3
#define BC 12   // NB*NC
#define N1 255
#define N2 127
#define N3 63
#define N4 31
#define EPS 1e-5f
#define NPIX (NB * N1 * N1)   // 260100

// ---------------- workspace layout (float offsets) ----------------
// S8: AoS float4 {g,s,gg,gs} per site [bc][255][255]
constexpr size_t S8_OFF = 0;
constexpr size_t S8_SZ  = 4ull * BC * N1 * N1;
// CV*: interleaved v2f {cov,var}
constexpr size_t CV16_OFF = S8_OFF + S8_SZ;
constexpr size_t CV16_SZ  = 2ull * BC * N2 * N2;
constexpr size_t CV32_OFF = CV16_OFF + CV16_SZ;
constexpr size_t CV32_SZ  = 2ull * BC * N3 * N3;
constexpr size_t CV64_OFF = CV32_OFF + CV32_SZ;
constexpr size_t CV64_SZ  = 2ull * BC * N4 * N4;
// AB: interleaved v2f {A, b} per site
constexpr size_t AB_OFF = CV64_OFF + CV64_SZ;
constexpr size_t AB_SZ  = 2ull * NB * NC * N1 * N1;
// folded BN constants: inv1[48] bia1[48] inv2[48] bia2[48]
constexpr size_t IB_OFF = AB_OFF + AB_SZ;

// ---------------- kernel 1: 8x8 stride-4 box sums, 4 output rows/block --------
// Block covers output rows 4b..4b+3 (input rows 16b..16b+19, 20 rows for 4
// outputs -> 1.25x read overlap vs 1.5x before). Column sums of 4-row groups
// kept in registers; two smem phases; smem writes are float4 (conflict-free).
__global__ __launch_bounds__(256) void base_kernel(
    const float* __restrict__ guide, const float* __restrict__ src,
    float4* __restrict__ S8q)
{
    __shared__ float smem[8][WW];  // planes: [rowsel*4+q][col]

    int b  = blockIdx.x % 64;
    int bc = blockIdx.x / 64;
    int t  = threadIdx.x;          // cols 4t..4t+3

    const float* gbase = guide + (size_t)bc * HH * WW + 4 * t;
    const float* sbase = src   + (size_t)bc * HH * WW + 4 * t;

    // col sums for one 4-row group -> c[q][k], q: g,s,gg,gs
    auto load_grp = [&](int g, float c[4][4]) {
#pragma unroll
        for (int q = 0; q < 4; ++q)
#pragma unroll
            for (int k = 0; k < 4; ++k) c[q][k] = 0.f;
#pragma unroll
        for (int r = 0; r < 4; ++r) {
            int row = 16 * b + 4 * g + r;
            if (row < HH) {  // block-uniform; false only b=63, g=4
                float4 g4 = *(const float4*)(gbase + (size_t)row * WW);
                float4 s4 = *(const float4*)(sbase + (size_t)row * WW);
                float ge[4] = {g4.x, g4.y, g4.z, g4.w};
                float se[4] = {s4.x, s4.y, s4.z, s4.w};
#pragma unroll
                for (int k = 0; k < 4; ++k) {
                    c[0][k] += ge[k];
                    c[1][k] += se[k];
                    c[2][k] += ge[k] * ge[k];
                    c[3][k] += ge[k] * se[k];
                }
            }
        }
    };

    auto store_combo = [&](int rowsel, const float a[4][4], const float bb[4][4]) {
#pragma unroll
        for (int q = 0; q < 4; ++q) {
            float4 v;
            v.x = a[q][0] + bb[q][0];
            v.y = a[q][1] + bb[q][1];
            v.z = a[q][2] + bb[q][2];
            v.w = a[q][3] + bb[q][3];
            *(float4*)&smem[rowsel * 4 + q][4 * t] = v;  // contiguous b128
        }
    };

    auto emit = [&](int rowsel, int i) {
        if (t < N1 && i < N1) {
            float qv[4];
#pragma unroll
            for (int q = 0; q < 4; ++q) {
                const float* arr = smem[rowsel * 4 + q];
                float4 a4 = *(const float4*)(arr + 4 * t);
                float4 b4 = *(const float4*)(arr + 4 * t + 4);
                qv[q] = (a4.x + a4.y) + (a4.z + a4.w) +
                        (b4.x + b4.y) + (b4.z + b4.w);
            }
            float4 o4; o4.x = qv[0]; o4.y = qv[1]; o4.z = qv[2]; o4.w = qv[3];
            S8q[(size_t)bc * N1 * N1 + (size_t)i * N1 + t] = o4;
        }
    };

    float c0[4][4], c1[4][4], c2[4][4];
    // phase A: groups 0,1,2 -> output rows 4b, 4b+1
    load_grp(0, c0);
    load_grp(1, c1);
    load_grp(2, c2);
    store_combo(0, c0, c1);
    store_combo(1, c1, c2);
    __syncthreads();
    emit(0, 4 * b + 0);
    emit(1, 4 * b + 1);
    __syncthreads();
    // phase B: groups 3,4 (reuse c2) -> output rows 4b+2, 4b+3
    load_grp(3, c1);
    load_grp(4, c0);
    store_combo(0, c2, c1);
    store_combo(1, c1, c0);
    __syncthreads();
    emit(0, 4 * b + 2);
    emit(1, 4 * b + 3);
}

// ---------------- kernel 2: all pyramid stats + BN constant fold --------------
__global__ __launch_bounds__(256) void pyr_all(
    const float4* __restrict__ S8q, v2f* __restrict__ CV16,
    v2f* __restrict__ CV32, v2f* __restrict__ CV64,
    const float* __restrict__ g1, const float* __restrict__ b1,
    const float* __restrict__ rm1, const float* __restrict__ rv1,
    const float* __restrict__ g2, const float* __restrict__ b2,
    const float* __restrict__ rm2, const float* __restrict__ rv2,
    float* __restrict__ invbia)
{
    if (blockIdx.x == 0 && threadIdx.x < 48) {
        int o = threadIdx.x;
        float iv = g1[o] * rsqrtf(rv1[o] + EPS);
        invbia[o]      = iv;
        invbia[48 + o] = b1[o] - rm1[o] * iv;
        float iv2 = g2[o] * rsqrtf(rv2[o] + EPS);
        invbia[96 + o]  = iv2;
        invbia[144 + o] = b2[o] - rm2[o] * iv2;
    }

    const int n2t = BC * N2 * N2, n3t = BC * N3 * N3, n4t = BC * N4 * N4;
    int idx = blockIdx.x * 256 + threadIdx.x;

    v2f* CV; int nout, cnt; float invN; int rem;
    if (idx < n2t)              { CV = CV16; nout = N2; cnt = 2; invN = 1.f / 256.f;  rem = idx; }
    else if (idx < n2t + n3t)   { CV = CV32; nout = N3; cnt = 4; invN = 1.f / 1024.f; rem = idx - n2t; }
    else if (idx < n2t + n3t + n4t) { CV = CV64; nout = N4; cnt = 8; invN = 1.f / 4096.f; rem = idx - n2t - n3t; }
    else return;

    int j  = rem % nout;
    int tt = rem / nout;
    int i  = tt % nout;
    int bc = tt / nout;

    const float4* P = S8q + (size_t)bc * N1 * N1;
    int p0 = cnt * i, q0 = cnt * j;

    float s0 = 0.f, s1 = 0.f, s2 = 0.f, s3 = 0.f;
    for (int ky = 0; ky < cnt; ++ky) {
        size_t roff = (size_t)(p0 + 2 * ky) * N1 + q0;
        for (int kx = 0; kx < cnt; ++kx) {
            float4 q4 = P[roff + 2 * kx];
            s0 += q4.x; s1 += q4.y; s2 += q4.z; s3 += q4.w;
        }
    }

    size_t o = (size_t)bc * nout * nout + (size_t)i * nout + j;
    float mx = s0 * invN, my = s1 * invN;
    v2f cv; cv[0] = s3 * invN - mx * my; cv[1] = s2 * invN - mx * mx;
    CV[o] = cv;
}

// ---------------- kernel 3: MLP with scalar-path weights ----------------------
// Weight addresses are wave-uniform (compile-time offsets off a uniform
// pointer) -> compiler emits s_load through the scalar K$ (14.4 KB, fully
// K$-resident). NO LDS in this kernel: the LDS return path was the 36 us
// bottleneck of rounds 1-3. Math: channel-pair v_pk_fma, 1 pixel/thread.
__global__ __launch_bounds__(256) void mlp_kernel(
    const float4* __restrict__ S8q,
    const v2f* __restrict__ CV16, const v2f* __restrict__ CV32,
    const v2f* __restrict__ CV64,
    const float* __restrict__ w1, const float* __restrict__ w2,
    const float* __restrict__ w3, const float* __restrict__ invbia,
    v2f* __restrict__ AB)
{
    int idx = blockIdx.x * 256 + threadIdx.x;
    if (idx >= NPIX) return;
    int ox = idx % N1;
    int r  = idx / N1;
    int oy = r % N1;
    int b  = r / N1;

    float feats[24], mx1[3], my1[3];

    // level 1 (r=8) stats from raw sums
#pragma unroll
    for (int c = 0; c < 3; ++c) {
        float4 q4 = S8q[(size_t)(b * 3 + c) * N1 * N1 + (size_t)oy * N1 + ox];
        float mx = q4.x * (1.f / 64.f), my = q4.y * (1.f / 64.f);
        mx1[c] = mx; my1[c] = my;
        feats[c]     = q4.w * (1.f / 64.f) - mx * my;
        feats[3 + c] = q4.z * (1.f / 64.f) - mx * mx;
    }

    // levels 2..4: bilinear (align_corners) gather of {cov,var}
    const v2f* CVs[3]   = {CV16, CV32, CV64};
    const int nins[3]   = {N2, N3, N4};
    const float scales[3] = {(float)(126.0 / 254.0), (float)(62.0 / 254.0),
                             (float)(30.0 / 254.0)};
#pragma unroll
    for (int l = 0; l < 3; ++l) {
        const v2f* CV = CVs[l];
        int nin = nins[l];
        float sc = scales[l];
        float py = (float)oy * sc;
        int   i0 = min(max((int)floorf(py), 0), nin - 2);
        float wy = py - (float)i0;
        float px = (float)ox * sc;
        int   j0 = min(max((int)floorf(px), 0), nin - 2);
        float wx = px - (float)j0;
        int fo = 6 + 6 * l;
#pragma unroll
        for (int c = 0; c < 3; ++c) {
            size_t o00 = (size_t)(b * 3 + c) * nin * nin + (size_t)i0 * nin + j0;
            v2f c00 = CV[o00], c01 = CV[o00 + 1];
            v2f c10 = CV[o00 + nin], c11 = CV[o00 + nin + 1];
            v2f res = (c00 * (1.f - wy) + c10 * wy) * (1.f - wx) +
                      (c01 * (1.f - wy) + c11 * wy) * wx;
            feats[fo + c]     = res[0];
            feats[fo + 3 + c] = res[1];
        }
    }

    v2f f2[12];
#pragma unroll
    for (int k = 0; k < 12; ++k) { f2[k][0] = feats[2 * k]; f2[k][1] = feats[2 * k + 1]; }

    // MLP 24->48->48->3; weights via scalar loads, packed-f32 dot products
    v2f h1v[24];
#pragma unroll
    for (int o = 0; o < 48; ++o) {
        v2f acc = {0.f, 0.f};
#pragma unroll
        for (int k = 0; k < 12; ++k) {
            v2f wv = *(const v2f*)(w1 + o * 24 + 2 * k);  // uniform -> s_load
            acc += wv * f2[k];
        }
        float v = fmaxf((acc[0] + acc[1]) * invbia[o] + invbia[48 + o], 0.f);
        h1v[o >> 1][o & 1] = v;
    }
    v2f h2v[24];
#pragma unroll
    for (int o = 0; o < 48; ++o) {
        v2f acc = {0.f, 0.f};
#pragma unroll
        for (int k = 0; k < 24; ++k) {
            v2f wv = *(const v2f*)(w2 + o * 48 + 2 * k);  // uniform -> s_load
            acc += wv * h1v[k];
        }
        float v = fmaxf((acc[0] + acc[1]) * invbia[96 + o] + invbia[144 + o], 0.f);
        h2v[o >> 1][o & 1] = v;
    }
#pragma unroll
    for (int c = 0; c < 3; ++c) {
        v2f acc = {0.f, 0.f};
#pragma unroll
        for (int k = 0; k < 24; ++k) {
            v2f wv = *(const v2f*)(w3 + c * 48 + 2 * k);  // uniform -> s_load
            acc += wv * h2v[k];
        }
        float a = acc[0] + acc[1];
        v2f ab; ab[0] = a; ab[1] = my1[c] - a * mx1[c];
        AB[(size_t)(b * 3 + c) * N1 * N1 + (size_t)oy * N1 + ox] = ab;
    }
}

// ---------------- kernel 4: fused upsample + apply ----------------
__global__ __launch_bounds__(256) void final_kernel(
    const float* __restrict__ guide, const v2f* __restrict__ AB,
    float* __restrict__ out)
{
    __shared__ v2f abH[N1 + 1];
    int blk = blockIdx.x;
    int bc  = blk / HH;
    int h   = blk % HH;

    const float scale = (float)(254.0 / 1023.0);
    float py = (float)h * scale;
    int   i0 = min(max((int)floorf(py), 0), N1 - 2);
    float wy = py - (float)i0;

    int t = threadIdx.x;
    if (t < N1) {
        size_t base = (size_t)bc * N1 * N1 + (size_t)i0 * N1 + t;
        v2f p0 = AB[base], p1 = AB[base + N1];
        abH[t] = p0 * (1.f - wy) + p1 * wy;
    }
    __syncthreads();

    const float* gp = guide + (size_t)bc * HH * WW + (size_t)h * WW;
    float*       op = out   + (size_t)bc * HH * WW + (size_t)h * WW;

    float4 g4 = *(const float4*)(gp + 4 * t);
    float ge[4] = {g4.x, g4.y, g4.z, g4.w};
    float oe[4];
#pragma unroll
    for (int k = 0; k < 4; ++k) {
        int w = 4 * t + k;
        float px = (float)w * scale;
        int   j0 = min(max((int)floorf(px), 0), N1 - 2);
        float wx = px - (float)j0;
        v2f ab = abH[j0] * (1.f - wx) + abH[j0 + 1] * wx;
        oe[k] = ab[0] * ge[k] + ab[1];
    }
    float4 o4; o4.x = oe[0]; o4.y = oe[1]; o4.z = oe[2]; o4.w = oe[3];
    *(float4*)(op + 4 * t) = o4;
}

// ---------------- launch ----------------
extern "C" void kernel_launch(void* const* d_in, const int* in_sizes, int n_in,
                              void* d_out, int out_size, void* d_ws, size_t ws_size,
                              hipStream_t stream)
{
    const float* guide = (const float*)d_in[0];
    const float* src   = (const float*)d_in[1];
    const float* w1    = (const float*)d_in[2];
    const float* g1    = (const float*)d_in[3];
    const float* b1    = (const float*)d_in[4];
    const float* rm1   = (const float*)d_in[5];
    const float* rv1   = (const float*)d_in[6];
    const float* w2    = (const float*)d_in[7];
    const float* g2    = (const float*)d_in[8];
    const float* b2    = (const float*)d_in[9];
    const float* rm2   = (const float*)d_in[10];
    const float* rv2   = (const float*)d_in[11];
    const float* w3    = (const float*)d_in[12];
    float*       out   = (float*)d_out;

    float* ws    = (float*)d_ws;
    float4* S8q  = (float4*)(ws + S8_OFF);
    v2f*   CV16  = (v2f*)(ws + CV16_OFF);
    v2f*   CV32  = (v2f*)(ws + CV32_OFF);
    v2f*   CV64  = (v2f*)(ws + CV64_OFF);
    v2f*   AB    = (v2f*)(ws + AB_OFF);
    float* invbia = ws + IB_OFF;

    base_kernel<<<BC * 64, 256, 0, stream>>>(guide, src, S8q);

    {
        int total = BC * (N2 * N2 + N3 * N3 + N4 * N4);
        pyr_all<<<(total + 255) / 256, 256, 0, stream>>>(
            S8q, CV16, CV32, CV64, g1, b1, rm1, rv1, g2, b2, rm2, rv2, invbia);
    }

    mlp_kernel<<<(NPIX + 255) / 256, 256, 0, stream>>>(
        S8q, CV16, CV32, CV64, w1, w2, w3, invbia, AB);

    final_kernel<<<BC * HH, 256, 0, stream>>>(guide, AB, out);
}